// Round 14
// baseline (58.468 us; speedup 1.0000x reference)
//
#include <hip/hip_runtime.h>

#define TOKENS 16384
#define KDIM   2048
#define NEXP   64
#define TOPK   6
#define NSTEPS (KDIM / 32)        // 64 global 32k-steps
#define BM     16                 // tokens per block
#define BK     64                 // k per staged chunk
#define NCH    (KDIM / BK)        // 32 chunks
#define XSB    (BM * BK)          // floats per x buffer (1024 = 4 KB)

typedef short short8 __attribute__((ext_vector_type(8)));   // 8 bf16 = 4 VGPR
typedef float f32x4  __attribute__((ext_vector_type(4)));

// Exact 3-way truncation split: f == bf(h) + bf(l) + bf(l2) + eps, |eps| <= 2^-24 |f|.
__device__ __forceinline__ void split3(float f, short& h, short& l, short& l2) {
  const unsigned u = __builtin_bit_cast(unsigned, f);
  h = (short)(u >> 16);
  const float r1 = f - __builtin_bit_cast(float, u & 0xffff0000u);
  const unsigned u1 = __builtin_bit_cast(unsigned, r1);
  l = (short)(u1 >> 16);
  const float r2 = r1 - __builtin_bit_cast(float, u1 & 0xffff0000u);
  l2 = (short)(__builtin_bit_cast(unsigned, r2) >> 16);
}

__device__ __forceinline__ void g2l16(const void* g, void* l) {
  __builtin_amdgcn_global_load_lds(
      (const __attribute__((address_space(1))) unsigned*)g,
      (__attribute__((address_space(3))) unsigned*)l, 16, 0, 0);
}

// Kernel 0: pack W into MFMA-B-fragment order, 3-term bf16 split.
// w*[s][nt][lane][j] = term of W[s*32 + (lane>>4)*8 + j][nt*16 + (lane&15)]
__global__ __launch_bounds__(256)
void moe_wpack(const float* __restrict__ wg, short* __restrict__ wh,
               short* __restrict__ wl, short* __restrict__ wl2) {
  const int tid = blockIdx.x * 256 + threadIdx.x;  // 0..16383 = (s, nt, lane)
  const int l  = tid & 63;
  const int nt = (tid >> 6) & 3;
  const int s  = tid >> 8;
  short8 a, b, c;
#pragma unroll
  for (int j = 0; j < 8; ++j) {
    const int k = s * 32 + (l >> 4) * 8 + j;
    const int n = nt * 16 + (l & 15);
    short xh, xl, xl2;
    split3(wg[(size_t)k * NEXP + n], xh, xl, xl2);
    a[j] = xh; b[j] = xl; c[j] = xl2;
  }
  *(short8*)(wh  + (size_t)tid * 8) = a;
  *(short8*)(wl  + (size_t)tid * 8) = b;
  *(short8*)(wl2 + (size_t)tid * 8) = c;
}

// Kernel 1: FUSED GEMM + softmax + top-k with the proven r13 pipeline.
// Block = 16 tokens x 64 experts x full K. Grid 1024 -> 4 blocks/CU =
// 16 waves/CU (r7's TLP) with ns=1: NO part[], NO kernel2. Wave nt owns one
// 16x16 expert tile. Per iter: [6 w-loads] -> vmcnt(6) (in-order: retires
// exactly DMA(c)) -> RAW s_barrier -> stage(c+1) 1 DMA/thread -> compute
// (w-use waits vmcnt(1): DMA(c+1) stays in flight). Epilogue: 4KB lg[]
// exchange + in-block softmax/top-k (r10's proven code).
__global__ __launch_bounds__(256, 4)
void moe_fused(const float* __restrict__ x, const short* __restrict__ wh,
               const short* __restrict__ wl, const short* __restrict__ wl2,
               float* __restrict__ out) {
  __shared__ float xs[2 * XSB];   // 8 KB, double-buffered
  __shared__ float lg[16][NEXP];  // 4 KB reduced logits

  const int t    = threadIdx.x;
  const int lane = t & 63;
  const int nt   = t >> 6;        // wave = expert tile: experts nt*16..+15
  const int row0 = blockIdx.x * BM;
  const int r15  = lane & 15;     // token row within tile
  const int kb   = lane >> 4;     // k-subgroup (8 k per 32k-step)

  // staging: 256 granules (16B), 1 per thread. S = (row T, slot Gp);
  // source granule G = (Gp&8) | ((Gp^T)&7) (involution). LDS dest linear.
  auto stage = [&](int b, int c) {
    const int T = t >> 4, Gp = t & 15;
    const int G = (Gp & 8) | ((Gp ^ T) & 7);
    g2l16(x + (size_t)(row0 + T) * KDIM + c * BK + G * 4,
          xs + (size_t)b * XSB + (size_t)t * 4);
  };

  f32x4 accB = {};   // hh term (magnitude ~1)
  f32x4 accS = {};   // correction terms (magnitude ~2^-8)

  const short8* __restrict__ whv  = (const short8*)wh;
  const short8* __restrict__ wlv  = (const short8*)wl;
  const short8* __restrict__ wl2v = (const short8*)wl2;

  stage(0, 0);

  for (int c = 0; c < NCH; ++c) {
    const int b = c & 1;
    // 1) w fragments for MY expert tile, both 32k-steps of this chunk
    const int fiA = (2 * c) * 256 + nt * 64 + lane;
    const short8 bh0 = whv[fiA],       bl0 = wlv[fiA],       bl20 = wl2v[fiA];
    const short8 bh1 = whv[fiA + 256], bl1 = wlv[fiA + 256], bl21 = wl2v[fiA + 256];
    __builtin_amdgcn_sched_barrier(0);

    // 2) retire exactly DMA(c): queue = [DMA(c):1][w:6]
    asm volatile("s_waitcnt vmcnt(6)" ::: "memory");
    __builtin_amdgcn_sched_barrier(0);
    __builtin_amdgcn_s_barrier();       // RAW barrier: no vmcnt(0) drain
    __builtin_amdgcn_sched_barrier(0);

    // 3) stage chunk c+1 into the other buffer (its readers passed the barrier)
    if (c + 1 < NCH) stage(b ^ 1, c + 1);
    __builtin_amdgcn_sched_barrier(0);

    // 4) compute chunk c: 2 k-steps on my 16x16 tile
#pragma unroll
    for (int s = 0; s < 2; ++s) {
      const short8 bh  = s ? bh1  : bh0;
      const short8 bl  = s ? bl1  : bl0;
      const short8 bl2 = s ? bl21 : bl20;
      const int Ga  = s * 8 + kb * 2;
      const int Gpa = (Ga & 8) | ((Ga ^ r15) & 7);
      const int Gpb = (Ga & 8) | (((Ga + 1) ^ r15) & 7);
      const float* xr = xs + (size_t)b * XSB + r15 * BK;
      const float4 xa = *(const float4*)(xr + Gpa * 4);
      const float4 xb = *(const float4*)(xr + Gpb * 4);
      short8 ah, al, al2;
#pragma unroll
      for (int e = 0; e < 4; ++e) {
        short h0, l0, m0, h1, l1, m1;
        split3(((const float*)&xa)[e], h0, l0, m0);
        split3(((const float*)&xb)[e], h1, l1, m1);
        ah[e] = h0; al[e] = l0; al2[e] = m0;
        ah[e + 4] = h1; al[e + 4] = l1; al2[e + 4] = m1;
      }
      accB = __builtin_amdgcn_mfma_f32_16x16x32_bf16(ah,  bh,  accB, 0, 0, 0);
      accS = __builtin_amdgcn_mfma_f32_16x16x32_bf16(al,  bh,  accS, 0, 0, 0);
      accS = __builtin_amdgcn_mfma_f32_16x16x32_bf16(ah,  bl,  accS, 0, 0, 0);
      accS = __builtin_amdgcn_mfma_f32_16x16x32_bf16(al,  bl,  accS, 0, 0, 0);
      accS = __builtin_amdgcn_mfma_f32_16x16x32_bf16(ah,  bl2, accS, 0, 0, 0);
      accS = __builtin_amdgcn_mfma_f32_16x16x32_bf16(al2, bh,  accS, 0, 0, 0);
    }
  }

  // ---- logits exchange. D: col=lane&15 (expert in tile), row=(lane>>4)*4+r.
#pragma unroll
  for (int r = 0; r < 4; ++r)
    lg[kb * 4 + r][nt * 16 + r15] = accB[r] + accS[r];
  __syncthreads();

  // ---- softmax + top-k: 16 lanes per token, 4 experts/lane (proven code)
  const int sub  = lane & 15;
  const int tokL = nt * 4 + kb;
  float v[4];
  {
    const float4 p = *(const float4*)(&lg[tokL][sub * 4]);
    v[0] = p.x; v[1] = p.y; v[2] = p.z; v[3] = p.w;
  }

  float m = fmaxf(fmaxf(v[0], v[1]), fmaxf(v[2], v[3]));
#pragma unroll
  for (int off = 1; off < 16; off <<= 1) m = fmaxf(m, __shfl_xor(m, off));
  const float p0 = expf(v[0] - m), p1 = expf(v[1] - m);
  const float p2 = expf(v[2] - m), p3 = expf(v[3] - m);
  float s = p0 + p1 + p2 + p3;
#pragma unroll
  for (int off = 1; off < 16; off <<= 1) s += __shfl_xor(s, off);
  v[0] = p0 / s; v[1] = p1 / s; v[2] = p2 / s; v[3] = p3 / s;

  float resv = 0.f; int resi = 0;
#pragma unroll
  for (int rr = 0; rr < TOPK; ++rr) {
    float bv = v[0]; int bi = sub * 4;
#pragma unroll
    for (int j = 1; j < 4; ++j)
      if (v[j] > bv) { bv = v[j]; bi = sub * 4 + j; }   // strict > : lowest idx on tie
#pragma unroll
    for (int off = 1; off < 16; off <<= 1) {
      const float ov = __shfl_xor(bv, off);
      const int   oi = __shfl_xor(bi, off);
      if (ov > bv || (ov == bv && oi < bi)) { bv = ov; bi = oi; }
    }
    if (sub == rr) { resv = bv; resi = bi; }
    if ((bi >> 2) == sub) v[bi & 3] = -1.f;   // scores > 0, sentinel safe
  }

  if (sub < TOPK) {
    const int tok = row0 + tokL;
    out[(size_t)tok * TOPK + sub] = (float)resi;
    out[(size_t)TOKENS * TOPK + (size_t)tok * TOPK + sub] = resv;
  }
}

extern "C" void kernel_launch(void* const* d_in, const int* in_sizes, int n_in,
                              void* d_out, int out_size, void* d_ws, size_t ws_size,
                              hipStream_t stream) {
  const float* x  = (const float*)d_in[0];
  const float* wg = (const float*)d_in[1];
  float* out = (float*)d_out;

  short* wh  = (short*)d_ws;                        // 3 x 131072 shorts = 768 KB
  short* wl  = wh + (size_t)NSTEPS * 4 * 64 * 8;
  short* wl2 = wl + (size_t)NSTEPS * 4 * 64 * 8;

  moe_wpack<<<dim3(64), dim3(256), 0, stream>>>(wg, wh, wl, wl2);
  moe_fused<<<dim3(TOKENS / BM), dim3(256), 0, stream>>>(x, wh, wl, wl2, out);
}